// Round 6
// baseline (368.748 us; speedup 1.0000x reference)
//
#include <hip/hip_runtime.h>
#include <math.h>

#define BDIM 2
#define SLEN 2048
#define NH 16
#define NKV 4
#define HD 128

typedef __attribute__((ext_vector_type(8))) short short8v;
typedef __attribute__((ext_vector_type(4))) short short4v;
typedef __attribute__((ext_vector_type(8))) __bf16 bf16x8;
typedef __attribute__((ext_vector_type(4))) float f32x4;

__device__ inline unsigned short f2bf(float x) {
  unsigned int u = __builtin_bit_cast(unsigned int, x);
  unsigned int r = (u + 0x7fffu + ((u >> 16) & 1u)) >> 16;
  return (unsigned short)r;
}
__device__ inline float bf2f(unsigned short b) {
  unsigned int u = ((unsigned int)b) << 16;
  return __builtin_bit_cast(float, u);
}

// ---------------------------------------------------------------------------
// bf16 MFMA GEMM, m97 inner structure, 128x256 tile (m105: 823 TF @4k).
// C[M,N] = A[M,K] @ Bt[N,K]^T.  4 waves 2x2, per-wave 64x128, BK=64.
// SPLIT: cols < Nsplit -> C0 (stride S0), else C1 at col-Nsplit (stride S1).
// ---------------------------------------------------------------------------
template <bool BF16_OUT, bool SPLIT>
__global__ __launch_bounds__(256) void gemm_mfma_wide(
    const unsigned short* __restrict__ A, const unsigned short* __restrict__ Bt,
    void* __restrict__ C0, void* __restrict__ C1,
    int M, int N, int K, int Nsplit, int S0, int S1) {
  __shared__ __align__(16) unsigned short As[128 * 64];  // 16 KB
  __shared__ __align__(16) unsigned short Bs[256 * 64];  // 32 KB
  const int t    = threadIdx.x;
  const int lane = t & 63;
  const int w    = t >> 6;
  const int lg   = lane >> 4, l15 = lane & 15;
  const int wr   = w >> 1,    wc  = w & 1;
  const int bm = blockIdx.y * 128, bn = blockIdx.x * 256;

  // staging: thread covers row (t>>3) + i*32, k-col (t&7)*8 (16B)
  const int srow = t >> 3;
  const int scol = (t & 7) * 8;
  const unsigned short* gA = &A[(size_t)(bm + srow) * K + scol];
  const unsigned short* gB = &Bt[(size_t)(bn + srow) * K + scol];

  f32x4 acc[4][8];
#pragma unroll
  for (int m = 0; m < 4; ++m)
#pragma unroll
    for (int n = 0; n < 8; ++n) acc[m][n] = (f32x4){0.f, 0.f, 0.f, 0.f};

  for (int k0 = 0; k0 < K; k0 += 64) {
    __syncthreads();
#pragma unroll
    for (int i = 0; i < 4; ++i)
      __builtin_amdgcn_global_load_lds(
          (const __attribute__((address_space(1))) unsigned int*)(gA + (size_t)i * 32 * K + k0),
          (__attribute__((address_space(3))) unsigned int*)&As[(srow + i * 32) * 64 + scol],
          16, 0, 0);
#pragma unroll
    for (int i = 0; i < 8; ++i)
      __builtin_amdgcn_global_load_lds(
          (const __attribute__((address_space(1))) unsigned int*)(gB + (size_t)i * 32 * K + k0),
          (__attribute__((address_space(3))) unsigned int*)&Bs[(srow + i * 32) * 64 + scol],
          16, 0, 0);
    __syncthreads();
#pragma unroll
    for (int kk = 0; kk < 2; ++kk) {
      bf16x8 a[4], b[8];
#pragma unroll
      for (int m = 0; m < 4; ++m)
        a[m] = __builtin_bit_cast(bf16x8, *reinterpret_cast<const short8v*>(
            &As[(wr * 64 + m * 16 + l15) * 64 + kk * 32 + lg * 8]));
#pragma unroll
      for (int n = 0; n < 8; ++n)
        b[n] = __builtin_bit_cast(bf16x8, *reinterpret_cast<const short8v*>(
            &Bs[(wc * 128 + n * 16 + l15) * 64 + kk * 32 + lg * 8]));
#pragma unroll
      for (int m = 0; m < 4; ++m)
#pragma unroll
        for (int n = 0; n < 8; ++n)
          acc[m][n] = __builtin_amdgcn_mfma_f32_16x16x32_bf16(a[m], b[n], acc[m][n], 0, 0, 0);
    }
  }

  // epilogue (D: lane reg j -> row lg*4+j, col l15)
  void* dst;
  int col0, stride;
  if (!SPLIT || bn < Nsplit) {
    dst = C0; col0 = bn; stride = S0;
  } else {
    dst = C1; col0 = bn - Nsplit; stride = S1;
  }
#pragma unroll
  for (int m = 0; m < 4; ++m) {
#pragma unroll
    for (int j = 0; j < 4; ++j) {
      const size_t row = (size_t)(bm + wr * 64 + m * 16 + lg * 4 + j);
#pragma unroll
      for (int n = 0; n < 8; ++n) {
        const int col = col0 + wc * 128 + n * 16 + l15;
        if (BF16_OUT)
          ((unsigned short*)dst)[row * stride + col] = f2bf(acc[m][n][j]);
        else
          ((float*)dst)[row * stride + col] = acc[m][n][j];
      }
    }
  }
}

// ---------------------------------------------------------------------------
__global__ __launch_bounds__(256) void transpose_cast(
    const float* __restrict__ W, unsigned short* __restrict__ Wt, int K, int N) {
  __shared__ float tile[32][33];
  const int tx = threadIdx.x & 31, ty = threadIdx.x >> 5;
  const int n0 = blockIdx.x * 32, k0 = blockIdx.y * 32;
#pragma unroll
  for (int i = 0; i < 4; ++i)
    tile[ty + i * 8][tx] = W[(size_t)(k0 + ty + i * 8) * N + n0 + tx];
  __syncthreads();
#pragma unroll
  for (int i = 0; i < 4; ++i)
    Wt[(size_t)(n0 + ty + i * 8) * K + k0 + tx] = f2bf(tile[tx][ty + i * 8]);
}

__global__ __launch_bounds__(256) void cast_f32_bf16(
    const float* __restrict__ in, unsigned short* __restrict__ out) {
  const int i = (blockIdx.x * 256 + threadIdx.x) * 8;
  float4 a = *reinterpret_cast<const float4*>(&in[i]);
  float4 b = *reinterpret_cast<const float4*>(&in[i + 4]);
  short8v s;
  s[0] = f2bf(a.x); s[1] = f2bf(a.y); s[2] = f2bf(a.z); s[3] = f2bf(a.w);
  s[4] = f2bf(b.x); s[5] = f2bf(b.y); s[6] = f2bf(b.z); s[7] = f2bf(b.w);
  *reinterpret_cast<short8v*>(&out[i]) = s;
}

// ---------------------------------------------------------------------------
__global__ __launch_bounds__(256) void rope_xpos_ip(
    unsigned short* __restrict__ buf, int row_stride, int nh_shift, int invert,
    float extra_scale) {
  const int idx = blockIdx.x * 256 + threadIdx.x;
  const int dp  = idx & 63;
  const int tmp = idx >> 6;
  const int h   = tmp & ((1 << nh_shift) - 1);
  const int row = tmp >> nh_shift;
  const int s   = row & (SLEN - 1);

  const float inv_freq = expf(-(float)dp * (9.210340371976184f / 64.0f));
  const float ang = (float)s * inv_freq;
  float sn, cs;
  sincosf(ang, &sn, &cs);

  unsigned short* p = buf + (size_t)row * row_stride + h * HD;
  const float x0 = bf2f(p[dp]);
  const float x1 = bf2f(p[dp + 64]);
  float y0 = x0 * cs - x1 * sn;
  float y1 = x1 * cs + x0 * sn;

  const float scl = ((float)s + 256.0f) / 512.0f;
  float se_even = invert ? (1.0f / scl) : scl;
  float se_odd  = invert ? scl : (1.0f / scl);
  float se = ((dp & 1) ? se_odd : se_even) * extra_scale;

  p[dp]      = f2bf(y0 * se);
  p[dp + 64] = f2bf(y1 * se);
}

// ---------------------------------------------------------------------------
// Flash attention v3 (unchanged from R5).
// ---------------------------------------------------------------------------
__global__ __launch_bounds__(256) void flash_attn_v3(
    const unsigned short* __restrict__ qb, const unsigned short* __restrict__ kvb,
    unsigned short* __restrict__ o) {
  const int bid = blockIdx.x;
  const int u   = bid & 31;
  const int qt  = (u & 1) ? (31 - (u >> 1)) : (u >> 1);
  const int bh  = bid >> 5;
  const int h   = bh & (NH - 1);
  const int b   = bh >> 4;
  const int kvh = h >> 2;

  __shared__ __align__(16) unsigned char smem[76800];
  unsigned short* KsBase = (unsigned short*)smem;
  unsigned int*   VwBase = (unsigned int*)(smem + 32768);
  unsigned short* Ps     = (unsigned short*)(smem + 65536);

  const int t    = threadIdx.x;
  const int lane = t & 63;
  const int w    = t >> 6;
  const int lg   = lane >> 4;
  const int l15  = lane & 15;

  bf16x8 qfrag[4];
  {
    const size_t qrow =
        ((size_t)(b * SLEN + qt * 64 + w * 16 + l15)) * (NH * HD) + h * HD;
#pragma unroll
    for (int kc = 0; kc < 4; ++kc)
      qfrag[kc] = __builtin_bit_cast(bf16x8,
          *reinterpret_cast<const short8v*>(&qb[qrow + kc * 32 + lg * 8]));
  }

  short8v kreg[4], vreg0[2], vreg1[2];
  const int kr_base = t >> 4, kc8 = t & 15;
  const int vr2 = t & 31, vc8_base = t >> 5;

#define LOAD_TILE(kt)                                                          \
  {                                                                            \
    const size_t kbase = ((size_t)(b * SLEN + (kt) * 64)) * 1024 + kvh * 128;  \
    _Pragma("unroll") for (int i = 0; i < 4; ++i)                              \
        kreg[i] = *reinterpret_cast<const short8v*>(                           \
            &kvb[kbase + (size_t)(kr_base + i * 16) * 1024 + kc8 * 8]);        \
    const size_t vbase = kbase + 512;                                          \
    _Pragma("unroll") for (int i = 0; i < 2; ++i) {                            \
      const int c8 = vc8_base + i * 8;                                         \
      vreg0[i] = *reinterpret_cast<const short8v*>(                            \
          &kvb[vbase + (size_t)(2 * vr2) * 1024 + c8 * 8]);                    \
      vreg1[i] = *reinterpret_cast<const short8v*>(                            \
          &kvb[vbase + (size_t)(2 * vr2 + 1) * 1024 + c8 * 8]);                \
    }                                                                          \
  }

#define STORE_TILE(bb)                                                         \
  {                                                                            \
    unsigned short* Kb = KsBase + (bb) * 8192;                                 \
    unsigned int*   Vw = VwBase + (bb) * 4096;                                 \
    _Pragma("unroll") for (int i = 0; i < 4; ++i) {                            \
      const int r = kr_base + i * 16;                                          \
      *reinterpret_cast<short8v*>(&Kb[r * 128 + ((kc8 * 8) ^ ((r & 7) << 3))]) \
          = kreg[i];                                                           \
    }                                                                          \
    _Pragma("unroll") for (int i = 0; i < 2; ++i) {                            \
      const int c8 = vc8_base + i * 8;                                         \
      _Pragma("unroll") for (int j = 0; j < 8; ++j) {                          \
        const int d = c8 * 8 + j;                                              \
        unsigned int wv = (unsigned int)(unsigned short)vreg0[i][j] |          \
                          ((unsigned int)(unsigned short)vreg1[i][j] << 16);   \
        Vw[d * 32 + (vr2 ^ ((d & 7) << 2))] = wv;                              \
      }                                                                        \
    }                                                                          \
  }

  f32x4 Oacc[8];
#pragma unroll
  for (int dt = 0; dt < 8; ++dt) Oacc[dt] = (f32x4){0.f, 0.f, 0.f, 0.f};
  float m_run = -1e30f, l_run = 0.f;

  LOAD_TILE(0)
  STORE_TILE(0)
  __syncthreads();
  int cur = 0;

  for (int kt = 0; kt <= qt; ++kt) {
    if (kt < qt) LOAD_TILE(kt + 1)

    const unsigned short* Kb = KsBase + cur * 8192;
    const unsigned int*   Vw = VwBase + cur * 4096;

    f32x4 S[4];
    __builtin_amdgcn_s_setprio(1);
#pragma unroll
    for (int ct = 0; ct < 4; ++ct) {
      f32x4 acc = (f32x4){0.f, 0.f, 0.f, 0.f};
      const int row = ct * 16 + l15;
#pragma unroll
      for (int kc = 0; kc < 4; ++kc) {
        bf16x8 kf = __builtin_bit_cast(bf16x8, *reinterpret_cast<const short8v*>(
            &Kb[row * 128 + ((kc * 32 + lg * 8) ^ ((row & 7) << 3))]));
        acc = __builtin_amdgcn_mfma_f32_16x16x32_bf16(kf, qfrag[kc], acc, 0, 0, 0);
      }
      S[ct] = acc;
    }
    __builtin_amdgcn_s_setprio(0);

    if (kt == qt) {
      const int ql = w * 16 + l15;
#pragma unroll
      for (int ct = 0; ct < 4; ++ct) {
#pragma unroll
        for (int j = 0; j < 4; ++j) {
          if (ct * 16 + lg * 4 + j > ql) S[ct][j] = -1e30f;
        }
      }
    }

    float pmax = S[0][0];
#pragma unroll
    for (int ct = 0; ct < 4; ++ct)
#pragma unroll
      for (int j = 0; j < 4; ++j) pmax = fmaxf(pmax, S[ct][j]);
    pmax = fmaxf(pmax, __shfl_xor(pmax, 16));
    pmax = fmaxf(pmax, __shfl_xor(pmax, 32));

    const bool defer = __all(pmax - m_run <= 8.0f);
    float m_new, f;
    if (defer) {
      m_new = m_run; f = 1.0f;
    } else {
      m_new = fmaxf(m_run, pmax);
      f = __expf(m_run - m_new);
      m_run = m_new;
    }

    float psum = 0.f;
#pragma unroll
    for (int ct = 0; ct < 4; ++ct) {
      short4v pk;
#pragma unroll
      for (int j = 0; j < 4; ++j) {
        const float pv = __expf(S[ct][j] - m_new);
        psum += pv;
        pk[j] = (short)f2bf(pv);
      }
      *reinterpret_cast<short4v*>(&Ps[w * 1408 + l15 * 88 + ct * 16 + lg * 4]) = pk;
    }
    psum += __shfl_xor(psum, 16);
    psum += __shfl_xor(psum, 32);
    l_run = l_run * f + psum;

    if (!defer) {
#pragma unroll
      for (int dt = 0; dt < 8; ++dt)
#pragma unroll
        for (int j = 0; j < 4; ++j) Oacc[dt][j] *= f;
    }

    const unsigned short* prow = &Ps[w * 1408 + l15 * 88];
#pragma unroll
    for (int kc = 0; kc < 2; ++kc) {
      bf16x8 pf = __builtin_bit_cast(bf16x8,
          *reinterpret_cast<const short8v*>(&prow[kc * 32 + lg * 8]));
      __builtin_amdgcn_s_setprio(1);
#pragma unroll
      for (int dt = 0; dt < 8; ++dt) {
        const int d = dt * 16 + l15;
        bf16x8 vf = __builtin_bit_cast(bf16x8, *reinterpret_cast<const bf16x8*>(
            &Vw[d * 32 + ((kc * 16 + lg * 4) ^ ((d & 7) << 2))]));
        Oacc[dt] = __builtin_amdgcn_mfma_f32_16x16x32_bf16(vf, pf, Oacc[dt], 0, 0, 0);
      }
      __builtin_amdgcn_s_setprio(0);
    }

    if (kt < qt) STORE_TILE(cur ^ 1)
    __syncthreads();
    cur ^= 1;
  }

  const float linv = 1.0f / l_run;
  const size_t row = (size_t)(b * SLEN + qt * 64 + w * 16 + l15);
#pragma unroll
  for (int dt = 0; dt < 8; ++dt) {
    short4v ov;
#pragma unroll
    for (int j = 0; j < 4; ++j) ov[j] = (short)f2bf(Oacc[dt][j] * linv);
    *reinterpret_cast<short4v*>(&o[row * 2048 + h * HD + dt * 16 + lg * 4]) = ov;
  }
#undef LOAD_TILE
#undef STORE_TILE
}

// ---------------------------------------------------------------------------
extern "C" void kernel_launch(void* const* d_in, const int* in_sizes, int n_in,
                              void* d_out, int out_size, void* d_ws, size_t ws_size,
                              hipStream_t stream) {
  (void)in_sizes; (void)n_in; (void)out_size; (void)ws_size;
  const float* x  = (const float*)d_in[0];
  const float* Wq = (const float*)d_in[1];
  const float* Wk = (const float*)d_in[2];
  const float* Wv = (const float*)d_in[3];
  const float* Wo = (const float*)d_in[4];
  float* out = (float*)d_out;

  unsigned char* ws = (unsigned char*)d_ws;
  const size_t MB = 1024 * 1024;
  unsigned short* xb    = (unsigned short*)(ws);            // 16 MB 4096x2048
  unsigned short* Wqkvt = (unsigned short*)(ws + 16 * MB);  // 12 MB 3072x2048
  unsigned short* Wot   = (unsigned short*)(ws + 28 * MB);  //  8 MB 2048x2048
  unsigned short* qb    = (unsigned short*)(ws + 36 * MB);  // 16 MB 4096x2048
  unsigned short* kvb   = (unsigned short*)(ws + 52 * MB);  //  8 MB 4096x1024
  unsigned short* attn  = (unsigned short*)(ws + 60 * MB);  // 16 MB

  const int M = BDIM * SLEN;  // 4096
  dim3 blk(256);

  cast_f32_bf16<<<(M * 2048) / (256 * 8), blk, 0, stream>>>(x, xb);
  // merged Bt: rows 0-2047 Wq^T, 2048-2559 Wk^T, 2560-3071 Wv^T
  transpose_cast<<<dim3(64, 64), blk, 0, stream>>>(Wq, Wqkvt, 2048, 2048);
  transpose_cast<<<dim3(16, 64), blk, 0, stream>>>(
      Wk, Wqkvt + (size_t)2048 * 2048, 2048, 512);
  transpose_cast<<<dim3(16, 64), blk, 0, stream>>>(
      Wv, Wqkvt + (size_t)2560 * 2048, 2048, 512);
  transpose_cast<<<dim3(64, 64), blk, 0, stream>>>(Wo, Wot, 2048, 2048);

  // fused QKV projection: N=3072, split dest qb (stride 2048) / kvb (stride 1024)
  gemm_mfma_wide<true, true><<<dim3(3072 / 256, M / 128), blk, 0, stream>>>(
      xb, Wqkvt, qb, kvb, M, 3072, 2048, 2048, 2048, 1024);

  rope_xpos_ip<<<(M * NH * 64) / 256, blk, 0, stream>>>(
      qb, 2048, 4, 0, 0.088388347648318447f);
  rope_xpos_ip<<<(M * NKV * 64) / 256, blk, 0, stream>>>(kvb, 1024, 2, 1, 1.0f);

  flash_attn_v3<<<BDIM * NH * (SLEN / 64), blk, 0, stream>>>(qb, kvb, attn);

  gemm_mfma_wide<false, false><<<dim3(2048 / 256, M / 128), blk, 0, stream>>>(
      attn, Wot, out, nullptr, M, 2048, 2048, 2048, 2048, 0);
}

// Round 7
// 292.548 us; speedup vs baseline: 1.2605x; 1.2605x over previous
//
#include <hip/hip_runtime.h>
#include <math.h>

#define BDIM 2
#define SLEN 2048
#define NH 16
#define NKV 4
#define HD 128

typedef __attribute__((ext_vector_type(8))) short short8v;
typedef __attribute__((ext_vector_type(4))) short short4v;
typedef __attribute__((ext_vector_type(8))) __bf16 bf16x8;
typedef __attribute__((ext_vector_type(4))) float f32x4;

__device__ inline unsigned short f2bf(float x) {
  unsigned int u = __builtin_bit_cast(unsigned int, x);
  unsigned int r = (u + 0x7fffu + ((u >> 16) & 1u)) >> 16;
  return (unsigned short)r;
}
__device__ inline float bf2f(unsigned short b) {
  unsigned int u = ((unsigned int)b) << 16;
  return __builtin_bit_cast(float, u);
}

// ---------------------------------------------------------------------------
// bf16 MFMA GEMM, m97 structure, 128x128 tile (proven R5 config).
// C = A[M,K] @ Bt[N,K]^T. SPLIT epilogue: col<Nsplit -> C0(S0) else C1(S1).
// ---------------------------------------------------------------------------
template <bool BF16_OUT, bool SPLIT>
__global__ __launch_bounds__(256) void gemm_mfma_bt(
    const unsigned short* __restrict__ A, const unsigned short* __restrict__ Bt,
    void* __restrict__ C0, void* __restrict__ C1,
    int M, int N, int K, int Nsplit, int S0, int S1) {
  __shared__ __align__(16) unsigned short As[128 * 64];
  __shared__ __align__(16) unsigned short Bs[128 * 64];
  const int t    = threadIdx.x;
  const int lane = t & 63;
  const int w    = t >> 6;
  const int lg   = lane >> 4, l15 = lane & 15;
  const int wr   = w >> 1,    wc  = w & 1;
  const int bm = blockIdx.y * 128, bn = blockIdx.x * 128;

  const int srow = w * 32 + (lane >> 3);
  const int scol = (lane & 7) * 8;
  const unsigned short* gA = &A[(size_t)(bm + srow) * K + scol];
  const unsigned short* gB = &Bt[(size_t)(bn + srow) * K + scol];

  f32x4 acc[4][4];
#pragma unroll
  for (int m = 0; m < 4; ++m)
#pragma unroll
    for (int n = 0; n < 4; ++n) acc[m][n] = (f32x4){0.f, 0.f, 0.f, 0.f};

  for (int k0 = 0; k0 < K; k0 += 64) {
    __syncthreads();
#pragma unroll
    for (int i = 0; i < 4; ++i) {
      __builtin_amdgcn_global_load_lds(
          (const __attribute__((address_space(1))) unsigned int*)(gA + (size_t)i * 8 * K + k0),
          (__attribute__((address_space(3))) unsigned int*)&As[(w * 32 + i * 8) * 64],
          16, 0, 0);
      __builtin_amdgcn_global_load_lds(
          (const __attribute__((address_space(1))) unsigned int*)(gB + (size_t)i * 8 * K + k0),
          (__attribute__((address_space(3))) unsigned int*)&Bs[(w * 32 + i * 8) * 64],
          16, 0, 0);
    }
    __syncthreads();
#pragma unroll
    for (int kk = 0; kk < 2; ++kk) {
      bf16x8 a[4], b[4];
#pragma unroll
      for (int m = 0; m < 4; ++m)
        a[m] = __builtin_bit_cast(bf16x8, *reinterpret_cast<const short8v*>(
            &As[(wr * 64 + m * 16 + l15) * 64 + kk * 32 + lg * 8]));
#pragma unroll
      for (int n = 0; n < 4; ++n)
        b[n] = __builtin_bit_cast(bf16x8, *reinterpret_cast<const short8v*>(
            &Bs[(wc * 64 + n * 16 + l15) * 64 + kk * 32 + lg * 8]));
#pragma unroll
      for (int m = 0; m < 4; ++m)
#pragma unroll
        for (int n = 0; n < 4; ++n)
          acc[m][n] = __builtin_amdgcn_mfma_f32_16x16x32_bf16(a[m], b[n], acc[m][n], 0, 0, 0);
    }
  }

  void* dst;
  int col0, stride;
  if (!SPLIT || bn < Nsplit) {
    dst = C0; col0 = bn; stride = S0;
  } else {
    dst = C1; col0 = bn - Nsplit; stride = S1;
  }
#pragma unroll
  for (int m = 0; m < 4; ++m) {
#pragma unroll
    for (int j = 0; j < 4; ++j) {
      const size_t row = (size_t)(bm + wr * 64 + m * 16 + lg * 4 + j);
#pragma unroll
      for (int n = 0; n < 4; ++n) {
        const int col = col0 + wc * 64 + n * 16 + l15;
        if (BF16_OUT)
          ((unsigned short*)dst)[row * stride + col] = f2bf(acc[m][n][j]);
        else
          ((float*)dst)[row * stride + col] = acc[m][n][j];
      }
    }
  }
}

// ---------------------------------------------------------------------------
__global__ __launch_bounds__(256) void transpose_cast(
    const float* __restrict__ W, unsigned short* __restrict__ Wt, int K, int N) {
  __shared__ float tile[32][33];
  const int tx = threadIdx.x & 31, ty = threadIdx.x >> 5;
  const int n0 = blockIdx.x * 32, k0 = blockIdx.y * 32;
#pragma unroll
  for (int i = 0; i < 4; ++i)
    tile[ty + i * 8][tx] = W[(size_t)(k0 + ty + i * 8) * N + n0 + tx];
  __syncthreads();
#pragma unroll
  for (int i = 0; i < 4; ++i)
    Wt[(size_t)(n0 + ty + i * 8) * K + k0 + tx] = f2bf(tile[tx][ty + i * 8]);
}

__global__ __launch_bounds__(256) void cast_f32_bf16(
    const float* __restrict__ in, unsigned short* __restrict__ out) {
  const int i = (blockIdx.x * 256 + threadIdx.x) * 8;
  float4 a = *reinterpret_cast<const float4*>(&in[i]);
  float4 b = *reinterpret_cast<const float4*>(&in[i + 4]);
  short8v s;
  s[0] = f2bf(a.x); s[1] = f2bf(a.y); s[2] = f2bf(a.z); s[3] = f2bf(a.w);
  s[4] = f2bf(b.x); s[5] = f2bf(b.y); s[6] = f2bf(b.z); s[7] = f2bf(b.w);
  *reinterpret_cast<short8v*>(&out[i]) = s;
}

// ---------------------------------------------------------------------------
__global__ __launch_bounds__(256) void rope_xpos_ip(
    unsigned short* __restrict__ buf, int row_stride, int nh_shift, int invert,
    float extra_scale) {
  const int idx = blockIdx.x * 256 + threadIdx.x;
  const int dp  = idx & 63;
  const int tmp = idx >> 6;
  const int h   = tmp & ((1 << nh_shift) - 1);
  const int row = tmp >> nh_shift;
  const int s   = row & (SLEN - 1);

  const float inv_freq = expf(-(float)dp * (9.210340371976184f / 64.0f));
  const float ang = (float)s * inv_freq;
  float sn, cs;
  sincosf(ang, &sn, &cs);

  unsigned short* p = buf + (size_t)row * row_stride + h * HD;
  const float x0 = bf2f(p[dp]);
  const float x1 = bf2f(p[dp + 64]);
  float y0 = x0 * cs - x1 * sn;
  float y1 = x1 * cs + x0 * sn;

  const float scl = ((float)s + 256.0f) / 512.0f;
  float se_even = invert ? (1.0f / scl) : scl;
  float se_odd  = invert ? scl : (1.0f / scl);
  float se = ((dp & 1) ? se_odd : se_even) * extra_scale;

  p[dp]      = f2bf(y0 * se);
  p[dp + 64] = f2bf(y1 * se);
}

// ---------------------------------------------------------------------------
// Flash attention v4: 512 threads (8 waves), QBLK=128, KVBLK=64.
// Same per-wave math as v3 (swapped-operand, lane-local softmax, defer-max,
// dbuf K/V, 1 barrier/tile) but half the total tile iterations.
// ---------------------------------------------------------------------------
__global__ __launch_bounds__(512) void flash_attn_v4(
    const unsigned short* __restrict__ qb, const unsigned short* __restrict__ kvb,
    unsigned short* __restrict__ o) {
  const int bid = blockIdx.x;
  const int u   = bid & 15;
  const int qt2 = (u & 1) ? (15 - (u >> 1)) : (u >> 1);  // balanced pairing
  const int bh  = bid >> 4;
  const int h   = bh & (NH - 1);
  const int b   = bh >> 4;
  const int kvh = h >> 2;

  __shared__ __align__(16) unsigned char smem[88064];
  unsigned short* KsBase = (unsigned short*)smem;            // 2 x 64x128 swz
  unsigned int*   VwBase = (unsigned int*)(smem + 32768);    // 2 x 128x32 swz
  unsigned short* Ps     = (unsigned short*)(smem + 65536);  // 8 x [16][88]

  const int t    = threadIdx.x;
  const int lane = t & 63;
  const int w    = t >> 6;   // 0..7
  const int lg   = lane >> 4;
  const int l15  = lane & 15;

  // ---- Q fragments from global (wave w owns q-rows qt2*128 + w*16 + l15)
  bf16x8 qfrag[4];
  {
    const size_t qrow =
        ((size_t)(b * SLEN + qt2 * 128 + w * 16 + l15)) * (NH * HD) + h * HD;
#pragma unroll
    for (int kc = 0; kc < 4; ++kc)
      qfrag[kc] = __builtin_bit_cast(bf16x8,
          *reinterpret_cast<const short8v*>(&qb[qrow + kc * 32 + lg * 8]));
  }

  short8v kreg[2], vreg0, vreg1;
  const int kr_base = t >> 4, kc8 = t & 15;  // K: rows kr_base+32i, cols kc8*8
  const int vr2 = t & 31, vc8 = t >> 5;      // V: row-pair vr2, cols vc8*8

#define LOAD_TILE(kt)                                                          \
  {                                                                            \
    const size_t kbase = ((size_t)(b * SLEN + (kt) * 64)) * 1024 + kvh * 128;  \
    _Pragma("unroll") for (int i = 0; i < 2; ++i)                              \
        kreg[i] = *reinterpret_cast<const short8v*>(                           \
            &kvb[kbase + (size_t)(kr_base + i * 32) * 1024 + kc8 * 8]);        \
    const size_t vbase = kbase + 512;                                          \
    vreg0 = *reinterpret_cast<const short8v*>(                                 \
        &kvb[vbase + (size_t)(2 * vr2) * 1024 + vc8 * 8]);                     \
    vreg1 = *reinterpret_cast<const short8v*>(                                 \
        &kvb[vbase + (size_t)(2 * vr2 + 1) * 1024 + vc8 * 8]);                 \
  }

#define STORE_TILE(bb)                                                         \
  {                                                                            \
    unsigned short* Kb = KsBase + (bb) * 8192;                                 \
    unsigned int*   Vw = VwBase + (bb) * 4096;                                 \
    _Pragma("unroll") for (int i = 0; i < 2; ++i) {                            \
      const int r = kr_base + i * 32;                                          \
      *reinterpret_cast<short8v*>(&Kb[r * 128 + ((kc8 * 8) ^ ((r & 7) << 3))]) \
          = kreg[i];                                                           \
    }                                                                          \
    _Pragma("unroll") for (int j = 0; j < 8; ++j) {                            \
      const int d = vc8 * 8 + j;                                               \
      unsigned int wv = (unsigned int)(unsigned short)vreg0[j] |               \
                        ((unsigned int)(unsigned short)vreg1[j] << 16);        \
      Vw[d * 32 + (vr2 ^ ((d & 7) << 2))] = wv;                                \
    }                                                                          \
  }

  f32x4 Oacc[8];
#pragma unroll
  for (int dt = 0; dt < 8; ++dt) Oacc[dt] = (f32x4){0.f, 0.f, 0.f, 0.f};
  float m_run = -1e30f, l_run = 0.f;

  const int nt = 2 * qt2 + 2;  // kv tiles needed for this 128-row q block

  LOAD_TILE(0)
  STORE_TILE(0)
  __syncthreads();
  int cur = 0;

  for (int kt = 0; kt < nt; ++kt) {
    if (kt + 1 < nt) LOAD_TILE(kt + 1)

    const unsigned short* Kb = KsBase + cur * 8192;
    const unsigned int*   Vw = VwBase + cur * 4096;

    // ---- S^T = K @ Q^T : lane holds k = ct*16+lg*4+j for its q = l15
    f32x4 S[4];
    __builtin_amdgcn_s_setprio(1);
#pragma unroll
    for (int ct = 0; ct < 4; ++ct) {
      f32x4 acc = (f32x4){0.f, 0.f, 0.f, 0.f};
      const int row = ct * 16 + l15;
#pragma unroll
      for (int kc = 0; kc < 4; ++kc) {
        bf16x8 kf = __builtin_bit_cast(bf16x8, *reinterpret_cast<const short8v*>(
            &Kb[row * 128 + ((kc * 32 + lg * 8) ^ ((row & 7) << 3))]));
        acc = __builtin_amdgcn_mfma_f32_16x16x32_bf16(kf, qfrag[kc], acc, 0, 0, 0);
      }
      S[ct] = acc;
    }
    __builtin_amdgcn_s_setprio(0);

    if (kt >= 2 * qt2) {  // diagonal region: mask kv_local > q_local
      const int ql = w * 16 + l15 - (kt - 2 * qt2) * 64;
#pragma unroll
      for (int ct = 0; ct < 4; ++ct) {
#pragma unroll
        for (int j = 0; j < 4; ++j) {
          if (ct * 16 + lg * 4 + j > ql) S[ct][j] = -1e30f;
        }
      }
    }

    // ---- lane-local softmax (q = l15)
    float pmax = S[0][0];
#pragma unroll
    for (int ct = 0; ct < 4; ++ct)
#pragma unroll
      for (int j = 0; j < 4; ++j) pmax = fmaxf(pmax, S[ct][j]);
    pmax = fmaxf(pmax, __shfl_xor(pmax, 16));
    pmax = fmaxf(pmax, __shfl_xor(pmax, 32));

    const bool defer = __all(pmax - m_run <= 8.0f);
    float m_new, f;
    if (defer) {
      m_new = m_run; f = 1.0f;
    } else {
      m_new = fmaxf(m_run, pmax);
      f = __expf(m_run - m_new);
      m_run = m_new;
    }

    float psum = 0.f;
#pragma unroll
    for (int ct = 0; ct < 4; ++ct) {
      short4v pk;
#pragma unroll
      for (int j = 0; j < 4; ++j) {
        const float pv = __expf(S[ct][j] - m_new);
        psum += pv;
        pk[j] = (short)f2bf(pv);
      }
      *reinterpret_cast<short4v*>(&Ps[w * 1408 + l15 * 88 + ct * 16 + lg * 4]) = pk;
    }
    psum += __shfl_xor(psum, 16);
    psum += __shfl_xor(psum, 32);
    l_run = l_run * f + psum;

    if (!defer) {
#pragma unroll
      for (int dt = 0; dt < 8; ++dt)
#pragma unroll
        for (int j = 0; j < 4; ++j) Oacc[dt][j] *= f;
    }

    // ---- O^T += V^T @ P^T
    const unsigned short* prow = &Ps[w * 1408 + l15 * 88];
#pragma unroll
    for (int kc = 0; kc < 2; ++kc) {
      bf16x8 pf = __builtin_bit_cast(bf16x8,
          *reinterpret_cast<const short8v*>(&prow[kc * 32 + lg * 8]));
      __builtin_amdgcn_s_setprio(1);
#pragma unroll
      for (int dt = 0; dt < 8; ++dt) {
        const int d = dt * 16 + l15;
        bf16x8 vf = __builtin_bit_cast(bf16x8, *reinterpret_cast<const bf16x8*>(
            &Vw[d * 32 + ((kc * 16 + lg * 4) ^ ((d & 7) << 2))]));
        Oacc[dt] = __builtin_amdgcn_mfma_f32_16x16x32_bf16(vf, pf, Oacc[dt], 0, 0, 0);
      }
      __builtin_amdgcn_s_setprio(0);
    }

    if (kt + 1 < nt) STORE_TILE(cur ^ 1)
    __syncthreads();
    cur ^= 1;
  }

  const float linv = 1.0f / l_run;
  const size_t row = (size_t)(b * SLEN + qt2 * 128 + w * 16 + l15);
#pragma unroll
  for (int dt = 0; dt < 8; ++dt) {
    short4v ov;
#pragma unroll
    for (int j = 0; j < 4; ++j) ov[j] = (short)f2bf(Oacc[dt][j] * linv);
    *reinterpret_cast<short4v*>(&o[row * 2048 + h * HD + dt * 16 + lg * 4]) = ov;
  }
#undef LOAD_TILE
#undef STORE_TILE
}

// ---------------------------------------------------------------------------
extern "C" void kernel_launch(void* const* d_in, const int* in_sizes, int n_in,
                              void* d_out, int out_size, void* d_ws, size_t ws_size,
                              hipStream_t stream) {
  (void)in_sizes; (void)n_in; (void)out_size; (void)ws_size;
  const float* x  = (const float*)d_in[0];
  const float* Wq = (const float*)d_in[1];
  const float* Wk = (const float*)d_in[2];
  const float* Wv = (const float*)d_in[3];
  const float* Wo = (const float*)d_in[4];
  float* out = (float*)d_out;

  unsigned char* ws = (unsigned char*)d_ws;
  const size_t MB = 1024 * 1024;
  unsigned short* xb    = (unsigned short*)(ws);            // 16 MB 4096x2048
  unsigned short* Wqkvt = (unsigned short*)(ws + 16 * MB);  // 12 MB 3072x2048
  unsigned short* Wot   = (unsigned short*)(ws + 28 * MB);  //  8 MB 2048x2048
  unsigned short* qb    = (unsigned short*)(ws + 36 * MB);  // 16 MB 4096x2048
  unsigned short* kvb   = (unsigned short*)(ws + 52 * MB);  //  8 MB 4096x1024
  unsigned short* attn  = (unsigned short*)(ws + 60 * MB);  // 16 MB

  const int M = BDIM * SLEN;  // 4096
  dim3 blk(256);

  cast_f32_bf16<<<(M * 2048) / (256 * 8), blk, 0, stream>>>(x, xb);
  transpose_cast<<<dim3(64, 64), blk, 0, stream>>>(Wq, Wqkvt, 2048, 2048);
  transpose_cast<<<dim3(16, 64), blk, 0, stream>>>(
      Wk, Wqkvt + (size_t)2048 * 2048, 2048, 512);
  transpose_cast<<<dim3(16, 64), blk, 0, stream>>>(
      Wv, Wqkvt + (size_t)2560 * 2048, 2048, 512);
  transpose_cast<<<dim3(64, 64), blk, 0, stream>>>(Wo, Wot, 2048, 2048);

  // fused QKV projection at 128^2 tile: grid 24x32 = 768 blocks (3/CU)
  gemm_mfma_bt<true, true><<<dim3(24, 32), blk, 0, stream>>>(
      xb, Wqkvt, qb, kvb, M, 3072, 2048, 2048, 2048, 1024);

  rope_xpos_ip<<<(M * NH * 64) / 256, blk, 0, stream>>>(
      qb, 2048, 4, 0, 0.088388347648318447f);
  rope_xpos_ip<<<(M * NKV * 64) / 256, blk, 0, stream>>>(kvb, 1024, 2, 1, 1.0f);

  flash_attn_v4<<<BDIM * NH * (SLEN / 128), dim3(512), 0, stream>>>(qb, kvb, attn);

  gemm_mfma_bt<false, false><<<dim3(16, 32), blk, 0, stream>>>(
      attn, Wot, out, nullptr, M, 2048, 2048, 2048, 2048, 0);
}